// Round 10
// baseline (221.655 us; speedup 1.0000x reference)
//
#include <hip/hip_runtime.h>

#define SS 4096
#define DD 1024
#define LL 16

typedef __attribute__((ext_vector_type(8))) short short8;
typedef __attribute__((ext_vector_type(4))) float fl4;
typedef __attribute__((ext_vector_type(2))) float fl2;

static __device__ __forceinline__ short f2bf(float f) {
    // round-to-nearest-even fp32 -> bf16 (inputs finite)
    unsigned u = __float_as_uint(f);
    u += 0x7FFFu + ((u >> 16) & 1u);
    return (short)(u >> 16);
}

static __device__ __forceinline__ short8 pack8(fl4 a, fl4 b) {
    short8 r;
    r[0] = f2bf(a[0]); r[1] = f2bf(a[1]); r[2] = f2bf(a[2]); r[3] = f2bf(a[3]);
    r[4] = f2bf(b[0]); r[5] = f2bf(b[1]); r[6] = f2bf(b[2]); r[7] = f2bf(b[3]);
    return r;
}

// 512 blocks x 512 thr (8 waves), 2 blocks/CU (LDS 36.5 KB). NO K-split:
// every prior variant split K=1024 across 8 waves, forcing a cross-wave
// score exchange (scr->bar->combine->bar) every 16 s -- an 8-wave convoy
// that kept k_main at ~70us / 1.9 TB/s with 85% stall (R3 PMC). Here wave
// wv computes FULL-K scores for its OWN 8 s-rows (32 MFMA K-steps, A-frags
// from a one-time 32 KB bf16 LDS staging of summ), exp in-register, e->LDS.
// Main body has ONE barrier (e ready) between scores and PV. Score loads =
// 8 independent 4 KB row streams/wave (deep, latency-friendly); PV re-reads
// the block's 256 KB from L2/L3, overlapped across blocks (no global sync).
// MFMA D layout: col(s)=lane&15, row(l)=(lane>>4)*4+reg  [m89-verified];
// B-rows duplicated o&7 -> cols 8..15 mirror cols 0..7 (ignored).
__global__ __launch_bounds__(512) void k_main(const float* __restrict__ mem,
                                              const float* __restrict__ summ,
                                              float* __restrict__ part,
                                              float* __restrict__ Zpart) {
    __shared__ short8 a_lds[32][64];     // 32 K-steps x 64 lanes x 16 B = 32 KB
    __shared__ float  e_lds[64][LL];     // 4 KB
    __shared__ float  z_lds[8][LL];      // 0.5 KB

    int blk = blockIdx.x;                // 512 = 8 b x 64 segments
    int b   = blk >> 6;
    int s0  = (blk & 63) << 6;           // 64 s per block
    int t    = threadIdx.x;
    int wv   = t >> 6;                   // 0..7
    int lane = t & 63;
    int o  = lane & 15;
    int qd = lane >> 4;

    // ---- one-time A staging: summ -> bf16 frags in LDS ----
    // K-step j needs lane (o,qd) to hold summ[o][j*32+qd*8 .. +8] as 8 bf16.
    // Pass p: thread t stages step j = p*8+wv at its own lane slot.
    #pragma unroll
    for (int p = 0; p < 4; ++p) {
        int j = p * 8 + wv;
        const float* ar = summ + o * DD + j * 32 + qd * 8;
        fl4 x0 = *(const fl4*)ar;
        fl4 x1 = *(const fl4*)(ar + 4);
        a_lds[j][lane] = pack8(x0, x1);
    }
    __syncthreads();

    const float* gb = mem + ((size_t)b * SS + s0) * DD;
    const float scale = 0.03125f;        // 1/sqrt(1024)

    // ---- scores: wave wv, rows [wv*8, +8), full K=1024 ----
    // Lane reads row wv*8+(o&7) (lanes 8..15 duplicate -> same cache lines).
    fl4 acc = {0.f, 0.f, 0.f, 0.f};
    {
        const float* brow = gb + (size_t)(wv * 8 + (o & 7)) * DD + qd * 8;
        #pragma unroll
        for (int j = 0; j < 32; ++j) {
            fl4 f0 = *(const fl4*)(brow + j * 32);
            fl4 f1 = *(const fl4*)(brow + j * 32 + 4);
            short8 af = a_lds[j][lane];  // ds_read_b128, conflict-free
            acc = __builtin_amdgcn_mfma_f32_16x16x32_bf16(af, pack8(f0, f1),
                                                          acc, 0, 0, 0);
        }
    }

    // ---- softmax numerator in-register; e -> LDS; per-wave Z partial ----
    fl4 ev;
    #pragma unroll
    for (int r = 0; r < 4; ++r) ev[r] = __expf(acc[r] * scale);

    fl4 zv = ev;                          // sum over the wave's 8 rows (o bits 0..2)
    #pragma unroll
    for (int r = 0; r < 4; ++r) {
        float v = zv[r];
        v += __shfl_xor(v, 1, 64);
        v += __shfl_xor(v, 2, 64);
        v += __shfl_xor(v, 4, 64);
        zv[r] = v;
    }
    if (o == 0) *(fl4*)&z_lds[wv][qd * 4] = zv;          // lanes 0,16,32,48
    if (o < 8)  *(fl4*)&e_lds[wv * 8 + o][qd * 4] = ev;  // e[s][l=qd*4+r]

    asm volatile("s_waitcnt lgkmcnt(0)" ::: "memory");
    __builtin_amdgcn_s_barrier();        // THE barrier: e_lds/z_lds visible
    __builtin_amdgcn_sched_barrier(0);

    // ---- PV: thread owns d-pair t*2; 64 s x 16 l fp32 FMA; mem L2/L3-hot ----
    fl2 ctx[LL];
    #pragma unroll
    for (int l = 0; l < LL; ++l) ctx[l] = (fl2){0.f, 0.f};

    const float* mrow = gb + t * 2;
    #pragma unroll 8
    for (int s = 0; s < 64; ++s) {
        fl2 m2 = *(const fl2*)(mrow + (size_t)s * DD);
        const fl4* er = (const fl4*)&e_lds[s][0];
        fl4 e0 = er[0], e1 = er[1], e2 = er[2], e3 = er[3];
        #pragma unroll
        for (int j = 0; j < 4; ++j) {
            ctx[j]      += e0[j] * m2;
            ctx[4 + j]  += e1[j] * m2;
            ctx[8 + j]  += e2[j] * m2;
            ctx[12 + j] += e3[j] * m2;
        }
    }

    // ---- epilogue: unnormalized partials [blk][l][d]; Zpart[blk][l] ----
    float* pp = part + (size_t)blk * LL * DD + t * 2;
    #pragma unroll
    for (int l = 0; l < LL; ++l) *(fl2*)(pp + (size_t)l * DD) = ctx[l];

    if (t < LL) {
        float Z = 0.f;
        #pragma unroll
        for (int w8 = 0; w8 < 8; ++w8) Z += z_lds[w8][t];
        Zpart[blk * LL + t] = Z;
    }
}

// out[b][d] = sum_l (w[l] / sum_seg Zpart) * sum_seg part[b*64+seg][l][d]
// 256 blocks x 256 thr; fl4 loads (16B/lane); 64 segs, 2 per thread
__global__ __launch_bounds__(256) void k_out(const float* __restrict__ part,
                                             const float* __restrict__ Zpart,
                                             const float* __restrict__ w,
                                             float* __restrict__ out) {
    int blkid = blockIdx.x;          // 256 = 8 b x 32 d-chunks of 32
    int b  = blkid >> 5;
    int d0 = (blkid & 31) << 5;
    int t = threadIdx.x;
    __shared__ float coef[LL];
    __shared__ fl4 red[32][8];       // [thread-group][d-quad]

    if (t < LL) {
        float Z = 0.f;
        #pragma unroll
        for (int s = 0; s < 64; ++s) Z += Zpart[(b * 64 + s) * LL + t];
        coef[t] = w[t] / Z;
    }
    __syncthreads();

    int dq = t & 7;                  // d-quad within 32-d chunk
    int sg = t >> 3;                 // 0..31; handles segs sg and sg+32
    fl4 acc = {0.f, 0.f, 0.f, 0.f};
    #pragma unroll
    for (int h = 0; h < 2; ++h) {
        const float* pb = part + (size_t)(b * 64 + sg + h * 32) * LL * DD + d0 + dq * 4;
        #pragma unroll
        for (int l = 0; l < LL; ++l) {
            fl4 v = *(const fl4*)(pb + (size_t)l * DD);
            acc += coef[l] * v;
        }
    }
    red[sg][dq] = acc;
    __syncthreads();

    if (t < 8) {
        fl4 s = {0.f, 0.f, 0.f, 0.f};
        #pragma unroll
        for (int g = 0; g < 32; ++g) s += red[g][t];
        *(fl4*)&out[b * DD + d0 + t * 4] = s;
    }
}

extern "C" void kernel_launch(void* const* d_in, const int* in_sizes, int n_in,
                              void* d_out, int out_size, void* d_ws, size_t ws_size,
                              hipStream_t stream) {
    const float* mem  = (const float*)d_in[0];  // [8,4096,1024] fp32
    const float* summ = (const float*)d_in[1];  // [16,1024] fp32
    const float* w    = (const float*)d_in[2];  // [1,16] fp32
    float* out = (float*)d_out;                 // [8,1024] fp32

    char* ws = (char*)d_ws;
    float* Zpart = (float*)ws;                  // 512*16 fl = 32 KB (pad to 64K)
    float* part  = (float*)(ws + 64 * 1024);    // 512*16*1024 fl = 32 MB

    k_main<<<512, 512, 0, stream>>>(mem, summ, part, Zpart);
    k_out<<<256, 256, 0, stream>>>(part, Zpart, w, out);
}

// Round 11
// 215.286 us; speedup vs baseline: 1.0296x; 1.0296x over previous
//
#include <hip/hip_runtime.h>

#define SS 4096
#define DD 1024
#define LL 16

typedef __attribute__((ext_vector_type(8))) short short8;
typedef __attribute__((ext_vector_type(4))) float fl4;
typedef __attribute__((ext_vector_type(2))) float fl2;

static __device__ __forceinline__ short f2bf(float f) {
    // round-to-nearest-even fp32 -> bf16 (inputs finite)
    unsigned u = __float_as_uint(f);
    u += 0x7FFFu + ((u >> 16) & 1u);
    return (short)(u >> 16);
}

static __device__ __forceinline__ short8 pack8(fl4 a, fl4 b) {
    short8 r;
    r[0] = f2bf(a[0]); r[1] = f2bf(a[1]); r[2] = f2bf(a[2]); r[3] = f2bf(a[3]);
    r[4] = f2bf(b[0]); r[5] = f2bf(b[1]); r[6] = f2bf(b[2]); r[7] = f2bf(b[3]);
    return r;
}

// 512 blocks x 512 thr (8 waves), 2 blocks/CU (LDS 36.5 KB). R10 structure
// (independent full-K waves, ONE barrier) + EXPLICIT DEEP BATCHING.
// R10 PMC: VGPR=36 -> compiler scheduled with ~zero prefetch depth; both
// phases latency-serialized (90us, 1.85 TB/s, VALU 16%, MFMA 1%, occ 41%,
// nothing saturated). Here: score loop batches 8 K-steps (16 fl4 loads =
// 8 KB/wave in flight, sched_barrier, 8 MFMAs; next batch's loads hoist
// over current MFMAs -> ~16-deep sustained). PV batches 8 m2 loads (L2-hot)
// ahead of 256 FMAs. Same op order as R10 -> bit-identical result.
// MFMA D layout: col(s)=lane&15, row(l)=(lane>>4)*4+reg  [m89-verified];
// B-rows duplicated o&7 -> cols 8..15 mirror cols 0..7 (ignored).
__global__ __launch_bounds__(512) void k_main(const float* __restrict__ mem,
                                              const float* __restrict__ summ,
                                              float* __restrict__ part,
                                              float* __restrict__ Zpart) {
    __shared__ short8 a_lds[32][64];     // 32 K-steps x 64 lanes x 16 B = 32 KB
    __shared__ float  e_lds[64][LL];     // 4 KB
    __shared__ float  z_lds[8][LL];      // 0.5 KB

    int blk = blockIdx.x;                // 512 = 8 b x 64 segments
    int b   = blk >> 6;
    int s0  = (blk & 63) << 6;           // 64 s per block
    int t    = threadIdx.x;
    int wv   = t >> 6;                   // 0..7
    int lane = t & 63;
    int o  = lane & 15;
    int qd = lane >> 4;

    // ---- one-time A staging: summ -> bf16 frags in LDS ----
    #pragma unroll
    for (int p = 0; p < 4; ++p) {
        int j = p * 8 + wv;
        const float* ar = summ + o * DD + j * 32 + qd * 8;
        fl4 x0 = *(const fl4*)ar;
        fl4 x1 = *(const fl4*)(ar + 4);
        a_lds[j][lane] = pack8(x0, x1);
    }
    __syncthreads();

    const float* gb = mem + ((size_t)b * SS + s0) * DD;
    const float scale = 0.03125f;        // 1/sqrt(1024)

    // ---- scores: wave wv, rows [wv*8,+8), full K=1024, 8-step batches ----
    fl4 acc = {0.f, 0.f, 0.f, 0.f};
    {
        const float* brow = gb + (size_t)(wv * 8 + (o & 7)) * DD + qd * 8;
        #pragma unroll
        for (int jb = 0; jb < 4; ++jb) {
            fl4 f0[8], f1[8];
            #pragma unroll
            for (int u = 0; u < 8; ++u) {
                f0[u] = *(const fl4*)(brow + (jb * 8 + u) * 32);
                f1[u] = *(const fl4*)(brow + (jb * 8 + u) * 32 + 4);
            }
            __builtin_amdgcn_sched_barrier(0);   // all 16 loads issued first
            #pragma unroll
            for (int u = 0; u < 8; ++u) {
                short8 af = a_lds[jb * 8 + u][lane];   // ds_read_b128
                acc = __builtin_amdgcn_mfma_f32_16x16x32_bf16(
                          af, pack8(f0[u], f1[u]), acc, 0, 0, 0);
            }
        }
    }

    // ---- softmax numerator in-register; e -> LDS; per-wave Z partial ----
    fl4 ev;
    #pragma unroll
    for (int r = 0; r < 4; ++r) ev[r] = __expf(acc[r] * scale);

    fl4 zv = ev;                          // sum over the wave's 8 rows
    #pragma unroll
    for (int r = 0; r < 4; ++r) {
        float v = zv[r];
        v += __shfl_xor(v, 1, 64);
        v += __shfl_xor(v, 2, 64);
        v += __shfl_xor(v, 4, 64);
        zv[r] = v;
    }
    if (o == 0) *(fl4*)&z_lds[wv][qd * 4] = zv;          // lanes 0,16,32,48
    if (o < 8)  *(fl4*)&e_lds[wv * 8 + o][qd * 4] = ev;  // e[s][l=qd*4+r]

    asm volatile("s_waitcnt lgkmcnt(0)" ::: "memory");
    __builtin_amdgcn_s_barrier();        // THE barrier: e_lds/z_lds visible
    __builtin_amdgcn_sched_barrier(0);

    // ---- PV: thread owns d-pair t*2; 64 s x 16 l; 8-s load batches ----
    fl2 ctx[LL];
    #pragma unroll
    for (int l = 0; l < LL; ++l) ctx[l] = (fl2){0.f, 0.f};

    const float* mrow = gb + t * 2;
    #pragma unroll
    for (int sb = 0; sb < 8; ++sb) {
        fl2 m2[8];
        #pragma unroll
        for (int u = 0; u < 8; ++u)
            m2[u] = *(const fl2*)(mrow + (size_t)(sb * 8 + u) * DD);
        __builtin_amdgcn_sched_barrier(0);   // 8 L2-hot loads in flight
        #pragma unroll
        for (int u = 0; u < 8; ++u) {
            int s = sb * 8 + u;
            const fl4* er = (const fl4*)&e_lds[s][0];
            fl4 e0 = er[0], e1 = er[1], e2 = er[2], e3 = er[3];
            #pragma unroll
            for (int j = 0; j < 4; ++j) {
                ctx[j]      += e0[j] * m2[u];
                ctx[4 + j]  += e1[j] * m2[u];
                ctx[8 + j]  += e2[j] * m2[u];
                ctx[12 + j] += e3[j] * m2[u];
            }
        }
    }

    // ---- epilogue: unnormalized partials [blk][l][d]; Zpart[blk][l] ----
    float* pp = part + (size_t)blk * LL * DD + t * 2;
    #pragma unroll
    for (int l = 0; l < LL; ++l) *(fl2*)(pp + (size_t)l * DD) = ctx[l];

    if (t < LL) {
        float Z = 0.f;
        #pragma unroll
        for (int w8 = 0; w8 < 8; ++w8) Z += z_lds[w8][t];
        Zpart[blk * LL + t] = Z;
    }
}

// out[b][d] = sum_l (w[l] / sum_seg Zpart) * sum_seg part[b*64+seg][l][d]
// 256 blocks x 256 thr; fl4 loads (16B/lane); 64 segs, 2 per thread
__global__ __launch_bounds__(256) void k_out(const float* __restrict__ part,
                                             const float* __restrict__ Zpart,
                                             const float* __restrict__ w,
                                             float* __restrict__ out) {
    int blkid = blockIdx.x;          // 256 = 8 b x 32 d-chunks of 32
    int b  = blkid >> 5;
    int d0 = (blkid & 31) << 5;
    int t = threadIdx.x;
    __shared__ float coef[LL];
    __shared__ fl4 red[32][8];       // [thread-group][d-quad]

    if (t < LL) {
        float Z = 0.f;
        #pragma unroll
        for (int s = 0; s < 64; ++s) Z += Zpart[(b * 64 + s) * LL + t];
        coef[t] = w[t] / Z;
    }
    __syncthreads();

    int dq = t & 7;                  // d-quad within 32-d chunk
    int sg = t >> 3;                 // 0..31; handles segs sg and sg+32
    fl4 acc = {0.f, 0.f, 0.f, 0.f};
    #pragma unroll
    for (int h = 0; h < 2; ++h) {
        const float* pb = part + (size_t)(b * 64 + sg + h * 32) * LL * DD + d0 + dq * 4;
        #pragma unroll
        for (int l = 0; l < LL; ++l) {
            fl4 v = *(const fl4*)(pb + (size_t)l * DD);
            acc += coef[l] * v;
        }
    }
    red[sg][dq] = acc;
    __syncthreads();

    if (t < 8) {
        fl4 s = {0.f, 0.f, 0.f, 0.f};
        #pragma unroll
        for (int g = 0; g < 32; ++g) s += red[g][t];
        *(fl4*)&out[b * DD + d0 + t * 4] = s;
    }
}

extern "C" void kernel_launch(void* const* d_in, const int* in_sizes, int n_in,
                              void* d_out, int out_size, void* d_ws, size_t ws_size,
                              hipStream_t stream) {
    const float* mem  = (const float*)d_in[0];  // [8,4096,1024] fp32
    const float* summ = (const float*)d_in[1];  // [16,1024] fp32
    const float* w    = (const float*)d_in[2];  // [1,16] fp32
    float* out = (float*)d_out;                 // [8,1024] fp32

    char* ws = (char*)d_ws;
    float* Zpart = (float*)ws;                  // 512*16 fl = 32 KB (pad to 64K)
    float* part  = (float*)(ws + 64 * 1024);    // 512*16*1024 fl = 32 MB

    k_main<<<512, 512, 0, stream>>>(mem, summ, part, Zpart);
    k_out<<<256, 256, 0, stream>>>(part, Zpart, w, out);
}